// Round 1
// baseline (286.952 us; speedup 1.0000x reference)
//
#include <hip/hip_runtime.h>

// out = joints @ R + t, R = RX(roll) @ RY(pitch) @ RZ(yaw), per reference.
// Memory-bound: 169 MB in + 169 MB out. Each thread handles 4 points
// (12 consecutive floats) via 3 aligned float4 loads/stores so the xyz
// stride-3 layout still coalesces at 16 B/lane.

__global__ __launch_bounds__(256) void Transform_38723425141290_kernel(
    const float* __restrict__ joints,
    const float* __restrict__ orient,
    const float* __restrict__ trans,
    float* __restrict__ out,
    long long n_groups,   // number of 4-point (12-float) groups
    long long n_points)   // total point count
{
    // --- rotation matrix (wave-uniform; orientation/translation are tiny,
    // cached reads) ---
    const float roll = orient[0], pitch = orient[1], yaw = orient[2];
    float sr, cr, sp, cp, sy, cy;
    sincosf(roll, &sr, &cr);
    sincosf(pitch, &sp, &cp);
    sincosf(yaw, &sy, &cy);

    const float R00 = cp * cy;
    const float R01 = -cp * sy;
    const float R02 = sp;
    const float R10 = sr * sp * cy + cr * sy;
    const float R11 = cr * cy - sr * sp * sy;
    const float R12 = -sr * cp;
    const float R20 = sr * sy - cr * sp * cy;
    const float R21 = cr * sp * sy + sr * cy;
    const float R22 = cr * cp;

    const float tx = trans[0], ty = trans[1], tz = trans[2];

    const long long g = (long long)blockIdx.x * blockDim.x + threadIdx.x;

    if (g < n_groups) {
        const float4* jp = reinterpret_cast<const float4*>(joints) + g * 3;
        float4 a = jp[0];
        float4 b = jp[1];
        float4 c = jp[2];

        // unpack 4 points from 12 floats
        // p0 = (a.x,a.y,a.z) p1 = (a.w,b.x,b.y) p2 = (b.z,b.w,c.x) p3 = (c.y,c.z,c.w)
        float ox0 = a.x * R00 + a.y * R10 + a.z * R20 + tx;
        float oy0 = a.x * R01 + a.y * R11 + a.z * R21 + ty;
        float oz0 = a.x * R02 + a.y * R12 + a.z * R22 + tz;

        float ox1 = a.w * R00 + b.x * R10 + b.y * R20 + tx;
        float oy1 = a.w * R01 + b.x * R11 + b.y * R21 + ty;
        float oz1 = a.w * R02 + b.x * R12 + b.y * R22 + tz;

        float ox2 = b.z * R00 + b.w * R10 + c.x * R20 + tx;
        float oy2 = b.z * R01 + b.w * R11 + c.x * R21 + ty;
        float oz2 = b.z * R02 + b.w * R12 + c.x * R22 + tz;

        float ox3 = c.y * R00 + c.z * R10 + c.w * R20 + tx;
        float oy3 = c.y * R01 + c.z * R11 + c.w * R21 + ty;
        float oz3 = c.y * R02 + c.z * R12 + c.w * R22 + tz;

        float4* op = reinterpret_cast<float4*>(out) + g * 3;
        op[0] = make_float4(ox0, oy0, oz0, ox1);
        op[1] = make_float4(oy1, oz1, ox2, oy2);
        op[2] = make_float4(oz2, ox3, oy3, oz3);
    }

    // scalar tail (n_points % 4 != 0) — dead for this shape, kept for safety
    const long long tail_base = n_groups * 4;
    const long long tail_idx = tail_base + g;
    if (g < (n_points - tail_base)) {
        const float x = joints[tail_idx * 3 + 0];
        const float y = joints[tail_idx * 3 + 1];
        const float z = joints[tail_idx * 3 + 2];
        out[tail_idx * 3 + 0] = x * R00 + y * R10 + z * R20 + tx;
        out[tail_idx * 3 + 1] = x * R01 + y * R11 + z * R21 + ty;
        out[tail_idx * 3 + 2] = x * R02 + y * R12 + z * R22 + tz;
    }
}

extern "C" void kernel_launch(void* const* d_in, const int* in_sizes, int n_in,
                              void* d_out, int out_size, void* d_ws, size_t ws_size,
                              hipStream_t stream) {
    const float* joints = (const float*)d_in[0];
    const float* orient = (const float*)d_in[1];
    const float* trans  = (const float*)d_in[2];
    float* out = (float*)d_out;

    const long long n_floats = (long long)in_sizes[0];
    const long long n_points = n_floats / 3;
    const long long n_groups = n_points / 4;

    const int block = 256;
    long long work = n_groups > 0 ? n_groups : 1;
    const long long grid = (work + block - 1) / block;

    Transform_38723425141290_kernel<<<dim3((unsigned)grid), dim3(block), 0, stream>>>(
        joints, orient, trans, out, n_groups, n_points);
}